// Round 1
// baseline (893.847 us; speedup 1.0000x reference)
//
#include <hip/hip_runtime.h>

#define NB   32
#define NN   2048
#define CIN  64
#define COUT 128
#define ADJ_EPS 1e-6f
#define BN_EPS  1e-5f

typedef __attribute__((ext_vector_type(8))) short short8;
typedef __attribute__((ext_vector_type(4))) float floatx4;

// ws layout (float units):
// [0..127] bnsum | [128..255] bnsumsq | [256..383] scale | [384..511] shift
// [512 ..) xsT bf16: NB*CIN*NN ushorts = 8 MB (pre-swizzled 16B granules by c&7)
// then ATt bf16: NB*(NN/64)*NN*64 ushorts = 256 MB (A^T tiles, pre-swizzled by m&7)
#define BN1_OFF 0
#define BN2_OFF 128
#define SC_OFF  256
#define SH_OFF  384
#define XST_OFF 512
#define ATT_OFF (512 + 2097152)

static __device__ __forceinline__ ushort f2bf(float f) {
    union { float f; unsigned u; } v; v.f = f;
    unsigned r = v.u + 0x7FFFu + ((v.u >> 16) & 1u);   // RNE
    return (ushort)(r >> 16);
}
static __device__ __forceinline__ float bf2f(ushort u) {
    return __uint_as_float(((unsigned)u) << 16);
}

static __device__ __forceinline__ void gload16(const void* g, void* l) {
    __builtin_amdgcn_global_load_lds(
        (const __attribute__((address_space(1))) unsigned int*)g,
        (__attribute__((address_space(3))) unsigned int*)l, 16, 0, 0);
}

// ---------------- K1: streaming pass over A ---------------------------------
// block = (b, nt): rows n0..n0+63, all m. Reads A rows coalesced (f32),
// accumulates row sums in registers, writes ATt[b][nt][m][64] bf16
// (granule-swizzled by m&7) and xsT[b][c][n0..n0+64] = bf16(x*inv)
// (granule-swizzled by c&7).
__global__ __launch_bounds__(256, 4) void k1_prep(const float* __restrict__ A,
                                                  const float* __restrict__ x,
                                                  ushort* __restrict__ xsT,
                                                  ushort* __restrict__ ATt) {
    __shared__ __align__(16) ushort ldsT[128 * 72];   // [m][64r] bf16, stride 72
    __shared__ float invr[64];
    int b  = blockIdx.x & 31;                         // batch -> XCD
    int nt = blockIdx.x >> 5;
    int n0 = nt * 64;
    int t  = threadIdx.x;
    int c4 = t & 31, r8 = t >> 5;                     // lane's float4-col, row group

    float racc[8];
#pragma unroll
    for (int i = 0; i < 8; ++i) racc[i] = 0.f;

    const float* Abase = A + ((size_t)b * NN + n0) * NN;
    int isw = (c4 & 7);                               // internal LDS swizzle = (m>>2)&7

    for (int mc = 0; mc < 16; ++mc) {
        int m0 = mc * 128;
        // load 8 rows (as 4 pairs), accumulate sums, write transposed bf16 to LDS
#pragma unroll
        for (int p = 0; p < 4; ++p) {
            int ra = r8 * 8 + 2 * p;                  // even row of the pair
            float4 va = *(const float4*)(Abase + (size_t)ra * NN + m0 + c4 * 4);
            float4 vb = *(const float4*)(Abase + (size_t)(ra + 1) * NN + m0 + c4 * 4);
            racc[2 * p]     += (va.x + va.y) + (va.z + va.w);
            racc[2 * p + 1] += (vb.x + vb.y) + (vb.z + vb.w);
            // ldsT[m][r-granule swizzled]: granule of ra is r8, in-granule off 2p
            int gsw = (r8 ^ isw) * 8 + 2 * p;
            ushort2 q0; q0.x = f2bf(va.x); q0.y = f2bf(vb.x);
            ushort2 q1; q1.x = f2bf(va.y); q1.y = f2bf(vb.y);
            ushort2 q2; q2.x = f2bf(va.z); q2.y = f2bf(vb.z);
            ushort2 q3; q3.x = f2bf(va.w); q3.y = f2bf(vb.w);
            *(ushort2*)&ldsT[(c4 * 4 + 0) * 72 + gsw] = q0;
            *(ushort2*)&ldsT[(c4 * 4 + 1) * 72 + gsw] = q1;
            *(ushort2*)&ldsT[(c4 * 4 + 2) * 72 + gsw] = q2;
            *(ushort2*)&ldsT[(c4 * 4 + 3) * 72 + gsw] = q3;
        }
        __syncthreads();
        // write out ATt chunk: thread t -> column m, 64 B contiguous
        {
            int m = t >> 1, h = t & 1;
            size_t obase = (((size_t)b * 32 + nt) * NN + m0 + m) * 64;
            int msw = (m >> 2) & 7;
#pragma unroll
            for (int s = 0; s < 4; ++s) {
                int slot  = h * 4 + s;                // global granule slot
                int gdata = slot ^ (m & 7);           // data granule (global swizzle)
                int gpos  = gdata ^ msw;              // position in LDS (internal swizzle)
                short8 v = *(const short8*)&ldsT[m * 72 + gpos * 8];
                *(short8*)&ATt[obase + slot * 8] = v;
            }
        }
        __syncthreads();
    }

    // finish row sums: butterfly across the 32 lanes sharing r8
#pragma unroll
    for (int i = 0; i < 8; ++i) {
#pragma unroll
        for (int off = 16; off; off >>= 1)
            racc[i] += __shfl_xor(racc[i], off);
    }
    if (c4 == 0) {
#pragma unroll
        for (int i = 0; i < 8; ++i)
            invr[r8 * 8 + i] = 1.f / (racc[i] + ADJ_EPS);
    }
    __syncthreads();
    // scale x rows, transpose to [c][n] bf16 in LDS (reuse ldsT, stride 72)
    {
        int c = t & 63, nq = t >> 6;
#pragma unroll
        for (int i = 0; i < 16; ++i) {
            int n = nq * 16 + i;
            float v = x[((size_t)b * NN + n0 + n) * CIN + c] * invr[n];
            ldsT[c * 72 + n] = f2bf(v);
        }
    }
    __syncthreads();
    // write xsT chunk (128 B per c), granule-swizzled by c&7
    if (t < 128) {
        int c = t >> 1, h = t & 1;
        size_t obase = ((size_t)b * CIN + c) * NN + n0;
#pragma unroll
        for (int s = 0; s < 4; ++s) {
            int slot  = h * 4 + s;
            int gdata = slot ^ (c & 7);
            short8 v = *(const short8*)&ldsT[c * 72 + gdata * 8];
            *(short8*)&xsT[obase + slot * 8] = v;
        }
    }
}

// ---------------- K2: xg = xs^T @ A via bf16 MFMA, global_load_lds staging ---
__global__ __launch_bounds__(256, 2) void k2_gemm(const ushort* __restrict__ ATt,
                                                  const ushort* __restrict__ xsT,
                                                  const float* __restrict__ W,
                                                  const float* __restrict__ bias,
                                                  float* __restrict__ hout,
                                                  float* __restrict__ bnsum,
                                                  float* __restrict__ bnsumsq) {
    // 0..32767: Att dbuf (2 x 16 KB) | 32768..49151: Xst dbuf (2 x 8 KB)
    // 49152..65535: Wb (bf16 packed pairs) | 65536..67583: bn partials
    // xg (32 KB, epilogue only) aliases the Att buffers.
    __shared__ __align__(16) char smem[67584];
    ushort* AttB = (ushort*)smem;
    ushort* XstB = (ushort*)(smem + 32768);
    float*  xg   = (float*)smem;
    ushort* wbu  = (ushort*)(smem + 49152);
    float*  bn1  = (float*)(smem + 65536);
    float*  bn2  = bn1 + 256;

    int b  = blockIdx.x & 31;                        // batch -> XCD (xsT L2 reuse)
    int m0 = (blockIdx.x >> 5) * 128;
    int t  = threadIdx.x;
    int w  = t >> 6, lane = t & 63;
    int l15 = lane & 15, q = lane >> 4;

    // one-time: stage W -> bf16 interleaved c-pairs
    {
        int c = t & 63, o0 = (t >> 6) * 32;
#pragma unroll
        for (int p = 0; p < 32; ++p) {
            int o = o0 + p;
            wbu[(c >> 1) * 256 + o * 2 + (c & 1)] = f2bf(W[o * CIN + c]);
        }
    }

    const ushort* Asrc = ATt + ((size_t)b * 32 * NN + m0) * 64;
    const ushort* Xsrc = xsT + (size_t)b * CIN * NN;

    auto stage = [&](int nt, int buf) {
        const ushort* ga = Asrc + (size_t)nt * (NN * 64);
        ushort* la = AttB + buf * 8192;
#pragma unroll
        for (int r = 0; r < 4; ++r)                   // 16 KB contiguous
            gload16(ga + (r * 256 + t) * 8, la + (r * 256 + t) * 8);
        ushort* lx = XstB + buf * 4096;
#pragma unroll
        for (int r = 0; r < 2; ++r) {                 // 64 rows x 128 B
            int c = (r * 256 + t) >> 3, g = t & 7;
            gload16(Xsrc + (size_t)c * NN + nt * 64 + g * 8, lx + c * 64 + g * 8);
        }
    };

    floatx4 acc[4][2];
#pragma unroll
    for (int ct = 0; ct < 4; ++ct)
#pragma unroll
        for (int j = 0; j < 2; ++j) {
            floatx4 z = {0.f, 0.f, 0.f, 0.f};
            acc[ct][j] = z;
        }

    stage(0, 0);
    __syncthreads();                                  // drains vmcnt -> buf0 ready

    for (int nt = 0; nt < 32; ++nt) {
        int cur = nt & 1;
        if (nt + 1 < 32) stage(nt + 1, cur ^ 1);      // in flight across compute
        const ushort* la = AttB + cur * 8192;
        const ushort* lx = XstB + cur * 4096;
#pragma unroll
        for (int kh = 0; kh < 2; ++kh) {              // K halves (granules 0-3 / 4-7)
            short8 af[4], bfr[2];
#pragma unroll
            for (int ct = 0; ct < 4; ++ct) {
                int row  = ct * 16 + l15;
                int slot = (kh * 4 + q) ^ (row & 7);
                af[ct] = *(const short8*)&lx[row * 64 + slot * 8];
            }
#pragma unroll
            for (int j = 0; j < 2; ++j) {
                int row  = (w * 2 + j) * 16 + l15;
                int slot = (kh * 4 + q) ^ (row & 7);
                bfr[j] = *(const short8*)&la[row * 64 + slot * 8];
            }
#pragma unroll
            for (int ct = 0; ct < 4; ++ct)
#pragma unroll
                for (int j = 0; j < 2; ++j)
                    acc[ct][j] = __builtin_amdgcn_mfma_f32_16x16x32_bf16(
                        af[ct], bfr[j], acc[ct][j], 0, 0, 0);
        }
        __syncthreads();                              // drains next-tile loads too
    }

    // dump accumulators -> xg[c][m] (aliases staging; all reads done)
#pragma unroll
    for (int ct = 0; ct < 4; ++ct)
#pragma unroll
        for (int j = 0; j < 2; ++j) {
            int col = (w * 2 + j) * 16 + l15;
#pragma unroll
            for (int r = 0; r < 4; ++r)
                xg[(ct * 16 + q * 4 + r) * 128 + col] = acc[ct][j][r];
        }
    __syncthreads();

    // epilogue: h[o,m] = b[o] + sum_c W[o,c]*xg[c,m]; store [b,m,o]; BN partials
    int o  = t & 127;
    int mq = t >> 7;
    float bo = bias[o];
    float s1 = 0.f, s2 = 0.f;
    const ushort2* Wb2 = (const ushort2*)wbu;
    for (int mc = 0; mc < 4; ++mc) {
        float h[16];
#pragma unroll
        for (int i = 0; i < 16; ++i) h[i] = bo;
#pragma unroll
        for (int c2 = 0; c2 < 32; ++c2) {
            ushort2 wp = Wb2[c2 * 128 + o];
            float w0 = bf2f(wp.x), w1 = bf2f(wp.y);
            const float* x0p = &xg[(2 * c2) * 128 + mq * 64 + mc * 16];
            const float* x1p = &xg[(2 * c2 + 1) * 128 + mq * 64 + mc * 16];
#pragma unroll
            for (int v = 0; v < 4; ++v) {
                float4 g0 = *(const float4*)&x0p[v * 4];
                float4 g1 = *(const float4*)&x1p[v * 4];
                h[v * 4 + 0] = fmaf(w0, g0.x, fmaf(w1, g1.x, h[v * 4 + 0]));
                h[v * 4 + 1] = fmaf(w0, g0.y, fmaf(w1, g1.y, h[v * 4 + 1]));
                h[v * 4 + 2] = fmaf(w0, g0.z, fmaf(w1, g1.z, h[v * 4 + 2]));
                h[v * 4 + 3] = fmaf(w0, g0.w, fmaf(w1, g1.w, h[v * 4 + 3]));
            }
        }
        size_t base = ((size_t)b * NN + m0 + mq * 64 + mc * 16) * COUT + o;
#pragma unroll
        for (int i = 0; i < 16; ++i) {
            float v = h[i];
            s1 += v;
            s2 = fmaf(v, v, s2);
            hout[base + (size_t)i * COUT] = v;        // lanes = consecutive o
        }
    }
    bn1[t] = s1;
    bn2[t] = s2;
    __syncthreads();
    if (t < 128) {
        atomicAdd(&bnsum[o],   bn1[t] + bn1[t + 128]);
        atomicAdd(&bnsumsq[o], bn2[t] + bn2[t + 128]);
    }
}

// ---------------- K3: finalize BN stats ------------------------------------
__global__ void k3_bnstats(const float* __restrict__ bnsum,
                           const float* __restrict__ bnsumsq,
                           const float* __restrict__ gamma,
                           const float* __restrict__ beta,
                           float* __restrict__ scale,
                           float* __restrict__ shift) {
    int o = threadIdx.x;
    if (o < COUT) {
        const float invn = 1.f / ((float)NB * (float)NN);
        float mean = bnsum[o] * invn;
        float var  = bnsumsq[o] * invn - mean * mean;
        float sc   = gamma[o] * rsqrtf(var + BN_EPS);
        scale[o] = sc;
        shift[o] = beta[o] - mean * sc;
    }
}

// ---------------- K4: in-place BN apply + ReLU ------------------------------
__global__ __launch_bounds__(256) void k4_bnapply(float* __restrict__ hout,
                                                  const float* __restrict__ scale,
                                                  const float* __restrict__ shift) {
    const float4* sc4 = (const float4*)scale;
    const float4* sh4 = (const float4*)shift;
    float4* h4 = (float4*)hout;
    const size_t n4 = (size_t)NB * NN * COUT / 4;
    for (size_t idx = (size_t)blockIdx.x * blockDim.x + threadIdx.x; idx < n4;
         idx += (size_t)gridDim.x * blockDim.x) {
        int o4 = (int)(idx & 31);
        float4 h = h4[idx];
        float4 s = sc4[o4];
        float4 f = sh4[o4];
        h.x = fmaxf(fmaf(h.x, s.x, f.x), 0.f);
        h.y = fmaxf(fmaf(h.y, s.y, f.y), 0.f);
        h.z = fmaxf(fmaf(h.z, s.z, f.z), 0.f);
        h.w = fmaxf(fmaf(h.w, s.w, f.w), 0.f);
        h4[idx] = h;
    }
}

extern "C" void kernel_launch(void* const* d_in, const int* in_sizes, int n_in,
                              void* d_out, int out_size, void* d_ws, size_t ws_size,
                              hipStream_t stream) {
    const float* x     = (const float*)d_in[0];
    const float* A     = (const float*)d_in[1];
    const float* W     = (const float*)d_in[2];
    const float* bvec  = (const float*)d_in[3];
    const float* gamma = (const float*)d_in[4];
    const float* beta  = (const float*)d_in[5];
    float* out = (float*)d_out;
    float* ws  = (float*)d_ws;

    float*  bnsum   = ws + BN1_OFF;
    float*  bnsumsq = ws + BN2_OFF;
    float*  scale   = ws + SC_OFF;
    float*  shift   = ws + SH_OFF;
    ushort* xsT     = (ushort*)(ws + XST_OFF);
    ushort* ATt     = (ushort*)(ws + ATT_OFF);

    hipMemsetAsync(bnsum, 0, 256 * sizeof(float), stream);

    k1_prep<<<NB * (NN / 64), 256, 0, stream>>>(A, x, xsT, ATt);
    k2_gemm<<<NB * (NN / 128), 256, 0, stream>>>(ATt, xsT, W, bvec, out, bnsum, bnsumsq);
    k3_bnstats<<<1, 128, 0, stream>>>(bnsum, bnsumsq, gamma, beta, scale, shift);
    k4_bnapply<<<2048, 256, 0, stream>>>(out, scale, shift);
}